// Round 2
// baseline (262.796 us; speedup 1.0000x reference)
//
#include <hip/hip_runtime.h>
#include <math.h>

#define NS        4
#define P_ELEMS   (96*96*96)          // 884736
#define BPS       216                 // blocks per sample; 216*4096 = P_ELEMS
#define TILE      4096                // floats per array per block
#define NCOPY     8                   // replicated global hists
#define NBLOCKS   (NS*BPS)            // 864  (<= 4 blocks/CU * 256 CU = 1024 co-resident)
// weight = exp2(-((xb-k)*WS)^2), WS = sqrt(2048/961*log2 e)
#define WS        1.75343855f
#define EPSR      1e-10f

typedef __attribute__((ext_vector_type(8)))  short short8;
typedef __attribute__((ext_vector_type(16))) float float16;

#define SCOPE_AGENT __HIP_MEMORY_SCOPE_AGENT

__device__ __forceinline__ float aload(const float* p) {
    return __hip_atomic_load(p, __ATOMIC_RELAXED, SCOPE_AGENT);
}
__device__ __forceinline__ void astore(float* p, float v) {
    __hip_atomic_store(p, v, __ATOMIC_RELAXED, SCOPE_AGENT);
}

// ws layout (floats): histall[32768] | counterB @32768 (self-zeroed) |
//                     counterA @33024 (zeroed by k_zero only) | pw4 @33040 (864*4)

__global__ void k_zero(unsigned* __restrict__ counterA) {
    if (threadIdx.x == 0)
        __hip_atomic_store(counterA, 0u, __ATOMIC_RELAXED, SCOPE_AGENT);
}

__global__ void __launch_bounds__(256, 4)
k_fused(const float* __restrict__ tar, const float* __restrict__ src,
        float* __restrict__ pw4, float* __restrict__ histall,
        unsigned* __restrict__ counterA, unsigned* __restrict__ counterB,
        float* __restrict__ out)
{
    __shared__ __align__(16) float lds[2 * TILE];   // 32 KB
    __shared__ float4 sred[4];
    __shared__ float bc[4];
    __shared__ float wres[4];
    __shared__ int lastflag;

    const int n = blockIdx.y, j = blockIdx.x;
    const int t = threadIdx.x;
    const int bid = n * BPS + j;
    const int lane = t & 63, wave = t >> 6;

    // ---- phase A: load tile (kept in registers across the barrier) + block minmax ----
    const float4* t4 = (const float4*)(tar + (size_t)n * P_ELEMS) + (size_t)j * (TILE / 4);
    const float4* s4 = (const float4*)(src + (size_t)n * P_ELEMS) + (size_t)j * (TILE / 4);
    float4 a0 = t4[t], a1 = t4[t + 256], a2 = t4[t + 512], a3 = t4[t + 768];
    float4 b0 = s4[t], b1 = s4[t + 256], b2 = s4[t + 512], b3 = s4[t + 768];

    float mnt = fminf(fminf(fminf(a0.x, a0.y), fminf(a0.z, a0.w)),
                      fminf(fminf(a1.x, a1.y), fminf(a1.z, a1.w)));
    mnt = fminf(mnt, fminf(fminf(fminf(a2.x, a2.y), fminf(a2.z, a2.w)),
                           fminf(fminf(a3.x, a3.y), fminf(a3.z, a3.w))));
    float mxt = fmaxf(fmaxf(fmaxf(a0.x, a0.y), fmaxf(a0.z, a0.w)),
                      fmaxf(fmaxf(a1.x, a1.y), fmaxf(a1.z, a1.w)));
    mxt = fmaxf(mxt, fmaxf(fmaxf(fmaxf(a2.x, a2.y), fmaxf(a2.z, a2.w)),
                           fmaxf(fmaxf(a3.x, a3.y), fmaxf(a3.z, a3.w))));
    float mns = fminf(fminf(fminf(b0.x, b0.y), fminf(b0.z, b0.w)),
                      fminf(fminf(b1.x, b1.y), fminf(b1.z, b1.w)));
    mns = fminf(mns, fminf(fminf(fminf(b2.x, b2.y), fminf(b2.z, b2.w)),
                           fminf(fminf(b3.x, b3.y), fminf(b3.z, b3.w))));
    float mxs = fmaxf(fmaxf(fmaxf(b0.x, b0.y), fmaxf(b0.z, b0.w)),
                      fmaxf(fmaxf(b1.x, b1.y), fmaxf(b1.z, b1.w)));
    mxs = fmaxf(mxs, fmaxf(fmaxf(fmaxf(b2.x, b2.y), fmaxf(b2.z, b2.w)),
                           fmaxf(fmaxf(b3.x, b3.y), fmaxf(b3.z, b3.w))));
    #pragma unroll
    for (int o = 32; o; o >>= 1) {
        mnt = fminf(mnt, __shfl_xor(mnt, o));
        mxt = fmaxf(mxt, __shfl_xor(mxt, o));
        mns = fminf(mns, __shfl_xor(mns, o));
        mxs = fmaxf(mxs, __shfl_xor(mxs, o));
    }
    if (lane == 0) sred[wave] = make_float4(mnt, mxt, mns, mxs);
    __syncthreads();
    if (t == 0) {
        float4 v0 = sred[0], v1 = sred[1], v2 = sred[2], v3 = sred[3];
        astore(&pw4[bid * 4 + 0], fminf(fminf(v0.x, v1.x), fminf(v2.x, v3.x)));
        astore(&pw4[bid * 4 + 1], fmaxf(fmaxf(v0.y, v1.y), fmaxf(v2.y, v3.y)));
        astore(&pw4[bid * 4 + 2], fminf(fminf(v0.z, v1.z), fminf(v2.z, v3.z)));
        astore(&pw4[bid * 4 + 3], fmaxf(fmaxf(v0.w, v1.w), fmaxf(v2.w, v3.w)));
    }
    // zero hist replicas + done-counter: floats [0, 33024) — excludes counterA and pw4
    if (bid < 129) astore(&histall[bid * 256 + t], 0.0f);

    // ---- software grid barrier (all 864 blocks co-resident by construction) ----
    __syncthreads();                       // all of this block's stores issued+drained
    if (t == 0) {
        __threadfence();                   // publish agent-wide
        __hip_atomic_fetch_add(counterA, 1u, __ATOMIC_RELEASE, SCOPE_AGENT);
        while (__hip_atomic_load(counterA, __ATOMIC_ACQUIRE, SCOPE_AGENT) < NBLOCKS)
            __builtin_amdgcn_s_sleep(2);
    }
    __syncthreads();

    // ---- phase B: reduce this sample's 216 partials, compute scales ----
    {
        float rmnt = INFINITY, rmxt = -INFINITY, rmns = INFINITY, rmxs = -INFINITY;
        if (t < BPS) {
            const float* p = pw4 + (n * BPS + t) * 4;
            rmnt = aload(p + 0); rmxt = aload(p + 1);
            rmns = aload(p + 2); rmxs = aload(p + 3);
        }
        #pragma unroll
        for (int o = 32; o; o >>= 1) {
            rmnt = fminf(rmnt, __shfl_xor(rmnt, o));
            rmxt = fmaxf(rmxt, __shfl_xor(rmxt, o));
            rmns = fminf(rmns, __shfl_xor(rmns, o));
            rmxs = fmaxf(rmxs, __shfl_xor(rmxs, o));
        }
        if (lane == 0) sred[wave] = make_float4(rmnt, rmxt, rmns, rmxs);
        __syncthreads();
        if (t == 0) {
            float4 v0 = sred[0], v1 = sred[1], v2 = sred[2], v3 = sred[3];
            bc[0] = fminf(fminf(v0.x, v1.x), fminf(v2.x, v3.x));
            bc[1] = fmaxf(fmaxf(v0.y, v1.y), fmaxf(v2.y, v3.y));
            bc[2] = fminf(fminf(v0.z, v1.z), fminf(v2.z, v3.z));
            bc[3] = fmaxf(fmaxf(v0.w, v1.w), fmaxf(v2.w, v3.w));
        }
        __syncthreads();
    }
    float gmnt = bc[0], gmns = bc[2];
    float fit = 31.0f * WS / (bc[1] - gmnt + 1e-12f);
    float fis = 31.0f * WS / (bc[3] - gmns + 1e-12f);

    // ---- stage pre-scaled bin coords from the registers we already hold ----
    {
        float4 v;
        v.x=(a0.x-gmnt)*fit; v.y=(a0.y-gmnt)*fit; v.z=(a0.z-gmnt)*fit; v.w=(a0.w-gmnt)*fit;
        ((float4*)lds)[t] = v;
        v.x=(a1.x-gmnt)*fit; v.y=(a1.y-gmnt)*fit; v.z=(a1.z-gmnt)*fit; v.w=(a1.w-gmnt)*fit;
        ((float4*)lds)[t + 256] = v;
        v.x=(a2.x-gmnt)*fit; v.y=(a2.y-gmnt)*fit; v.z=(a2.z-gmnt)*fit; v.w=(a2.w-gmnt)*fit;
        ((float4*)lds)[t + 512] = v;
        v.x=(a3.x-gmnt)*fit; v.y=(a3.y-gmnt)*fit; v.z=(a3.z-gmnt)*fit; v.w=(a3.w-gmnt)*fit;
        ((float4*)lds)[t + 768] = v;
        v.x=(b0.x-gmns)*fis; v.y=(b0.y-gmns)*fis; v.z=(b0.z-gmns)*fis; v.w=(b0.w-gmns)*fis;
        ((float4*)(lds + TILE))[t] = v;
        v.x=(b1.x-gmns)*fis; v.y=(b1.y-gmns)*fis; v.z=(b1.z-gmns)*fis; v.w=(b1.w-gmns)*fis;
        ((float4*)(lds + TILE))[t + 256] = v;
        v.x=(b2.x-gmns)*fis; v.y=(b2.y-gmns)*fis; v.z=(b2.z-gmns)*fis; v.w=(b2.w-gmns)*fis;
        ((float4*)(lds + TILE))[t + 512] = v;
        v.x=(b3.x-gmns)*fis; v.y=(b3.y-gmns)*fis; v.z=(b3.z-gmns)*fis; v.w=(b3.w-gmns)*fis;
        ((float4*)(lds + TILE))[t + 768] = v;
    }
    __syncthreads();

    // ---- phase C: MFMA joint histogram (validated loop; 64 iters/wave) ----
    const int g = lane >> 5;
    const float q = (float)(lane & 31) * WS;
    const float* xb = lds + wave * (TILE / 4);
    const float* yb = lds + TILE + wave * (TILE / 4);

    float16 acc;
    #pragma unroll
    for (int i = 0; i < 16; i++) acc[i] = 0.0f;

    #pragma unroll 4
    for (int it = 0; it < TILE / 4 / 16; it++) {     // 64 iterations, 16 elements each
        int kb = it * 16 + g * 8;
        float4 xa = *(const float4*)(xb + kb);
        float4 xc = *(const float4*)(xb + kb + 4);
        float4 ya = *(const float4*)(yb + kb);
        float4 yc = *(const float4*)(yb + kb + 4);
        float xs[8] = {xa.x, xa.y, xa.z, xa.w, xc.x, xc.y, xc.z, xc.w};
        float ys[8] = {ya.x, ya.y, ya.z, ya.w, yc.x, yc.y, yc.z, yc.w};
        unsigned av[8], bv[8];
        #pragma unroll
        for (int jj = 0; jj < 8; jj++) {
            float d = xs[jj] - q;
            float arg = -d * d;
            float w;
            asm("v_exp_f32 %0, %1" : "=v"(w) : "v"(arg));
            av[jj] = __float_as_uint(w);
            d = ys[jj] - q;
            arg = -d * d;
            asm("v_exp_f32 %0, %1" : "=v"(w) : "v"(arg));
            bv[jj] = __float_as_uint(w);
        }
        union { unsigned u[4]; short8 v; } af, bf;
        #pragma unroll
        for (int jj = 0; jj < 4; jj++) {
            af.u[jj] = __builtin_amdgcn_perm(av[2 * jj + 1], av[2 * jj], 0x07060302u);
            bf.u[jj] = __builtin_amdgcn_perm(bv[2 * jj + 1], bv[2 * jj], 0x07060302u);
        }
        acc = __builtin_amdgcn_mfma_f32_32x32x16_bf16(af.v, bf.v, acc, 0, 0, 0);
    }

    __syncthreads();
    {
        float* hw = lds + wave * 1024;
        int col = lane & 31;
        #pragma unroll
        for (int reg = 0; reg < 16; reg++) {
            int row = (reg & 3) + 8 * (reg >> 2) + 4 * g;
            hw[row * 32 + col] = acc[reg];
        }
    }
    __syncthreads();
    {
        float* histn = histall + ((j & (NCOPY - 1)) * NS + n) * 1024;
        for (int bb = t; bb < 1024; bb += 256) {
            float v = lds[bb] + lds[1024 + bb] + lds[2048 + bb] + lds[3072 + bb];
            unsafeAtomicAdd(&histn[bb], v);
        }
    }

    // ---- phase D: last block computes entropies + loss ----
    __threadfence();
    __syncthreads();
    if (t == 0) {
        unsigned old = __hip_atomic_fetch_add(counterB, 1u, __ATOMIC_ACQ_REL,
                                              SCOPE_AGENT);
        lastflag = (old == NBLOCKS - 1);
    }
    __syncthreads();
    if (!lastflag) return;

    float* sh = lds;                 // reuse 16 KB of staging LDS
    int nn = wave;
    float4 h[4];
    float part = 0.0f;
    #pragma unroll
    for (int r = 0; r < 4; r++) {
        float4 s = make_float4(0.f, 0.f, 0.f, 0.f);
        #pragma unroll
        for (int c = 0; c < NCOPY; c++) {
            const float* hp = histall + (c * NS + nn) * 1024 + (lane * 4 + r) * 4;
            s.x += aload(hp + 0); s.y += aload(hp + 1);
            s.z += aload(hp + 2); s.w += aload(hp + 3);
        }
        h[r] = s;
        part += (s.x + s.y) + (s.z + s.w);
    }
    #pragma unroll
    for (int o = 32; o; o >>= 1) part += __shfl_xor(part, o);
    float inv = 1.0f / part;
    float ej = 0.0f;
    #pragma unroll
    for (int r = 0; r < 4; r++) {
        float4 p;
        p.x = h[r].x * inv; p.y = h[r].y * inv; p.z = h[r].z * inv; p.w = h[r].w * inv;
        ((float4*)(sh + nn * 1024))[lane * 4 + r] = p;
        ej -= p.x * __logf(p.x + EPSR) + p.y * __logf(p.y + EPSR)
            + p.z * __logf(p.z + EPSR) + p.w * __logf(p.w + EPSR);
    }
    #pragma unroll
    for (int o = 32; o; o >>= 1) ej += __shfl_xor(ej, o);
    __syncthreads();
    float m = 0.0f;
    if (lane < 32) {
        int row = lane;
        for (int jj = 0; jj < 32; jj++) m += sh[nn * 1024 + row * 32 + ((jj + row) & 31)];
    } else {
        int col = lane - 32;
        for (int i = 0; i < 32; i++) m += sh[nn * 1024 + i * 32 + col];
    }
    float rc = -m * __logf(m + EPSR);
    #pragma unroll
    for (int o = 16; o; o >>= 1) rc += __shfl_xor(rc, o);   // halves reduce separately
    float es = __shfl(rc, 32);
    if (lane == 0) wres[nn] = (rc + es) / ej;
    __syncthreads();
    if (t == 0)
        out[0] = -(wres[0] + wres[1] + wres[2] + wres[3]) * 0.25f;
}

extern "C" void kernel_launch(void* const* d_in, const int* in_sizes, int n_in,
                              void* d_out, int out_size, void* d_ws, size_t ws_size,
                              hipStream_t stream) {
    const float* tar = (const float*)d_in[0];
    const float* src = (const float*)d_in[1];
    float* out = (float*)d_out;
    float* histall = (float*)d_ws;                         // 32768 floats
    unsigned* counterB = (unsigned*)(histall + 32768);     // zeroed in-kernel (pre-barrier)
    unsigned* counterA = (unsigned*)(histall + 33024);     // zeroed by k_zero
    float* pw4 = histall + 33040;                          // 864*4 floats

    k_zero<<<1, 64, 0, stream>>>(counterA);
    k_fused<<<dim3(BPS, NS), 256, 0, stream>>>(tar, src, pw4, histall,
                                               counterA, counterB, out);
}

// Round 3
// 237.244 us; speedup vs baseline: 1.1077x; 1.1077x over previous
//
#include <hip/hip_runtime.h>
#include <math.h>

#define N_SAMPLES 4
#define P_ELEMS   (96*96*96)          // 884736
// minmax geometry: deep loads, pure BW
#define MM_BPS    216
#define MM_T4     1024                // float4 per array per block (4/thread)
// hist geometry: validated MFMA loop
#define H_BPS     432
#define H_TILE    2048
#define H_T4      (H_TILE/4)          // 512 float4; 2 per thread per array
#define NCOPY     8                   // replicated global hists (contention / XCD spread)
#define NBLK_H    (H_BPS * N_SAMPLES) // 1728
// weight = exp(-(xb-k)^2 * 2048/961) = exp2(-((xb-k)*WS)^2), WS = sqrt(2048/961*log2 e)
#define WS        1.75343855f
#define EPSR      1e-10f

typedef __attribute__((ext_vector_type(8)))  short short8;
typedef __attribute__((ext_vector_type(16))) float float16;

#define SCOPE_AGENT __HIP_MEMORY_SCOPE_AGENT

__device__ __forceinline__ float aload(const float* p) {
    return __hip_atomic_load(p, __ATOMIC_RELAXED, SCOPE_AGENT);
}

// ws layout (floats): histall[32768] | counterB @32768 (zeroed by k_minmax) |
//                     pad to 33024  | pw4 (float4[864]) @33024

// ---------------- dispatch 1: per-block minmax partials + hist/counter zeroing ----------------

__global__ void __launch_bounds__(256)
k_minmax(const float* __restrict__ tar, const float* __restrict__ src,
         float4* __restrict__ pw, float* __restrict__ histall) {
    __shared__ float4 sred[4];
    int n = blockIdx.y, j = blockIdx.x;
    int t = threadIdx.x;
    const float4* t4 = (const float4*)(tar + (size_t)n * P_ELEMS) + (size_t)j * MM_T4;
    const float4* s4 = (const float4*)(src + (size_t)n * P_ELEMS) + (size_t)j * MM_T4;
    float4 a0 = t4[t], a1 = t4[t + 256], a2 = t4[t + 512], a3 = t4[t + 768];
    float4 b0 = s4[t], b1 = s4[t + 256], b2 = s4[t + 512], b3 = s4[t + 768];
    float mnt = fminf(fminf(fminf(a0.x, a0.y), fminf(a0.z, a0.w)),
                      fminf(fminf(a1.x, a1.y), fminf(a1.z, a1.w)));
    mnt = fminf(mnt, fminf(fminf(fminf(a2.x, a2.y), fminf(a2.z, a2.w)),
                           fminf(fminf(a3.x, a3.y), fminf(a3.z, a3.w))));
    float mxt = fmaxf(fmaxf(fmaxf(a0.x, a0.y), fmaxf(a0.z, a0.w)),
                      fmaxf(fmaxf(a1.x, a1.y), fmaxf(a1.z, a1.w)));
    mxt = fmaxf(mxt, fmaxf(fmaxf(fmaxf(a2.x, a2.y), fmaxf(a2.z, a2.w)),
                           fmaxf(fmaxf(a3.x, a3.y), fmaxf(a3.z, a3.w))));
    float mns = fminf(fminf(fminf(b0.x, b0.y), fminf(b0.z, b0.w)),
                      fminf(fminf(b1.x, b1.y), fminf(b1.z, b1.w)));
    mns = fminf(mns, fminf(fminf(fminf(b2.x, b2.y), fminf(b2.z, b2.w)),
                           fminf(fminf(b3.x, b3.y), fminf(b3.z, b3.w))));
    float mxs = fmaxf(fmaxf(fmaxf(b0.x, b0.y), fmaxf(b0.z, b0.w)),
                      fmaxf(fmaxf(b1.x, b1.y), fmaxf(b1.z, b1.w)));
    mxs = fmaxf(mxs, fmaxf(fmaxf(fmaxf(b2.x, b2.y), fmaxf(b2.z, b2.w)),
                           fmaxf(fmaxf(b3.x, b3.y), fmaxf(b3.z, b3.w))));
    #pragma unroll
    for (int o = 32; o; o >>= 1) {
        mnt = fminf(mnt, __shfl_xor(mnt, o));
        mxt = fmaxf(mxt, __shfl_xor(mxt, o));
        mns = fminf(mns, __shfl_xor(mns, o));
        mxs = fmaxf(mxs, __shfl_xor(mxs, o));
    }
    int lane = t & 63, wave = t >> 6;
    if (lane == 0) sred[wave] = make_float4(mnt, mxt, mns, mxs);
    __syncthreads();
    if (t == 0) {
        float4 v0 = sred[0], v1 = sred[1], v2 = sred[2], v3 = sred[3];
        float4 r;
        r.x = fminf(fminf(v0.x, v1.x), fminf(v2.x, v3.x));
        r.y = fmaxf(fmaxf(v0.y, v1.y), fmaxf(v2.y, v3.y));
        r.z = fminf(fminf(v0.z, v1.z), fminf(v2.z, v3.z));
        r.w = fmaxf(fmaxf(v0.w, v1.w), fmaxf(v2.w, v3.w));
        pw[n * MM_BPS + j] = r;
    }
    int bid = n * MM_BPS + j;
    // zero hist replicas (32768 floats) + counterB line (floats 32768..33023)
    if (bid < 129) histall[bid * 256 + t] = 0.0f;
}

// ---------------- dispatch 2: MFMA joint histogram + last-block entropy epilogue ----------------
// A-frag: lane (g=lane>>5, c=lane&31) supplies A[c][8g+j], B[8g+j][c], j=0..7.
// C/D: col = lane&31, row = (reg&3) + 8*(reg>>2) + 4*g.  (validated R3/R5/R6, absmax 0)

__global__ void __launch_bounds__(256, 8)
k_hist(const float* __restrict__ tar, const float* __restrict__ src,
       const float4* __restrict__ pw, float* __restrict__ histall,
       unsigned* __restrict__ counterB, float* __restrict__ out) {
    __shared__ __align__(16) float lds[2 * H_TILE];  // 16 KB
    __shared__ float4 sred[4];
    __shared__ float bc[4];
    __shared__ float wres[4];
    __shared__ int lastflag;
    int n = blockIdx.y, j = blockIdx.x;
    int t = threadIdx.x;

    // issue the big input loads first; they retire while we reduce partials
    const float4* t4 = (const float4*)(tar + (size_t)n * P_ELEMS) + (size_t)j * H_T4;
    const float4* s4 = (const float4*)(src + (size_t)n * P_ELEMS) + (size_t)j * H_T4;
    float4 a0 = t4[t], a1 = t4[t + 256];
    float4 b0 = s4[t], b1 = s4[t + 256];

    // reduce the sample's 216 minmax partials (L2-hot)
    {
        const float4* pwn = pw + n * MM_BPS;
        float mnt = INFINITY, mxt = -INFINITY, mns = INFINITY, mxs = -INFINITY;
        if (t < MM_BPS) {
            float4 v = pwn[t];
            mnt = v.x; mxt = v.y; mns = v.z; mxs = v.w;
        }
        #pragma unroll
        for (int o = 32; o; o >>= 1) {
            mnt = fminf(mnt, __shfl_xor(mnt, o));
            mxt = fmaxf(mxt, __shfl_xor(mxt, o));
            mns = fminf(mns, __shfl_xor(mns, o));
            mxs = fmaxf(mxs, __shfl_xor(mxs, o));
        }
        int lane = t & 63, wave = t >> 6;
        if (lane == 0) sred[wave] = make_float4(mnt, mxt, mns, mxs);
        __syncthreads();
        if (t == 0) {
            float4 v0 = sred[0], v1 = sred[1], v2 = sred[2], v3 = sred[3];
            bc[0] = fminf(fminf(v0.x, v1.x), fminf(v2.x, v3.x));
            bc[1] = fmaxf(fmaxf(v0.y, v1.y), fmaxf(v2.y, v3.y));
            bc[2] = fminf(fminf(v0.z, v1.z), fminf(v2.z, v3.z));
            bc[3] = fmaxf(fmaxf(v0.w, v1.w), fmaxf(v2.w, v3.w));
        }
        __syncthreads();
    }
    float mnt = bc[0], mns = bc[2];
    float fit = 31.0f * WS / (bc[1] - mnt + 1e-12f);
    float fis = 31.0f * WS / (bc[3] - mns + 1e-12f);

    // stage pre-scaled bin coords
    {
        float4 xo, yo;
        xo.x = (a0.x - mnt) * fit; xo.y = (a0.y - mnt) * fit;
        xo.z = (a0.z - mnt) * fit; xo.w = (a0.w - mnt) * fit;
        ((float4*)lds)[t] = xo;
        xo.x = (a1.x - mnt) * fit; xo.y = (a1.y - mnt) * fit;
        xo.z = (a1.z - mnt) * fit; xo.w = (a1.w - mnt) * fit;
        ((float4*)lds)[t + 256] = xo;
        yo.x = (b0.x - mns) * fis; yo.y = (b0.y - mns) * fis;
        yo.z = (b0.z - mns) * fis; yo.w = (b0.w - mns) * fis;
        ((float4*)(lds + H_TILE))[t] = yo;
        yo.x = (b1.x - mns) * fis; yo.y = (b1.y - mns) * fis;
        yo.z = (b1.z - mns) * fis; yo.w = (b1.w - mns) * fis;
        ((float4*)(lds + H_TILE))[t + 256] = yo;
    }
    __syncthreads();

    int lane = t & 63, wave = t >> 6, g = lane >> 5;
    float q = (float)(lane & 31) * WS;
    const float* xb = lds + wave * (H_TILE / 4);
    const float* yb = lds + H_TILE + wave * (H_TILE / 4);

    float16 acc;
    #pragma unroll
    for (int i = 0; i < 16; i++) acc[i] = 0.0f;

    #pragma unroll 4
    for (int it = 0; it < H_TILE / 4 / 16; it++) {   // 32 iterations, 16 elements each
        int kb = it * 16 + g * 8;
        float4 xa = *(const float4*)(xb + kb);
        float4 xc = *(const float4*)(xb + kb + 4);
        float4 ya = *(const float4*)(yb + kb);
        float4 yc = *(const float4*)(yb + kb + 4);
        float xs[8] = {xa.x, xa.y, xa.z, xa.w, xc.x, xc.y, xc.z, xc.w};
        float ys[8] = {ya.x, ya.y, ya.z, ya.w, yc.x, yc.y, yc.z, yc.w};
        unsigned av[8], bv[8];
        #pragma unroll
        for (int jj = 0; jj < 8; jj++) {
            float d = xs[jj] - q;
            float arg = -d * d;
            float w;
            asm("v_exp_f32 %0, %1" : "=v"(w) : "v"(arg));
            av[jj] = __float_as_uint(w);
            d = ys[jj] - q;
            arg = -d * d;
            asm("v_exp_f32 %0, %1" : "=v"(w) : "v"(arg));
            bv[jj] = __float_as_uint(w);
        }
        union { unsigned u[4]; short8 v; } af, bf;
        #pragma unroll
        for (int jj = 0; jj < 4; jj++) {
            af.u[jj] = __builtin_amdgcn_perm(av[2 * jj + 1], av[2 * jj], 0x07060302u);
            bf.u[jj] = __builtin_amdgcn_perm(bv[2 * jj + 1], bv[2 * jj], 0x07060302u);
        }
        acc = __builtin_amdgcn_mfma_f32_32x32x16_bf16(af.v, bf.v, acc, 0, 0, 0);
    }

    __syncthreads();
    {
        float* hw = lds + wave * 1024;
        int col = lane & 31;
        #pragma unroll
        for (int reg = 0; reg < 16; reg++) {
            int row = (reg & 3) + 8 * (reg >> 2) + 4 * g;
            hw[row * 32 + col] = acc[reg];
        }
    }
    __syncthreads();
    // merge into one of NCOPY replicated hists (spread over XCD round-robin)
    {
        float* histn = histall + ((j & (NCOPY - 1)) * N_SAMPLES + n) * 1024;
        for (int bb = t; bb < 1024; bb += 256) {
            float v = lds[bb] + lds[1024 + bb] + lds[2048 + bb] + lds[3072 + bb];
            unsafeAtomicAdd(&histn[bb], v);
        }
    }

    // ---- last-block epilogue: entropies + loss (validated R2 phase D) ----
    __threadfence();
    __syncthreads();
    if (t == 0) {
        unsigned old = __hip_atomic_fetch_add(counterB, 1u, __ATOMIC_ACQ_REL,
                                              SCOPE_AGENT);
        lastflag = (old == NBLK_H - 1);
    }
    __syncthreads();
    if (!lastflag) return;

    float* sh = lds;                 // reuse the 16 KB staging LDS
    int nn = wave;
    float4 h[4];
    float part = 0.0f;
    #pragma unroll
    for (int r = 0; r < 4; r++) {
        float4 s = make_float4(0.f, 0.f, 0.f, 0.f);
        #pragma unroll
        for (int c = 0; c < NCOPY; c++) {
            const float* hp = histall + (c * N_SAMPLES + nn) * 1024 + (lane * 4 + r) * 4;
            s.x += aload(hp + 0); s.y += aload(hp + 1);
            s.z += aload(hp + 2); s.w += aload(hp + 3);
        }
        h[r] = s;
        part += (s.x + s.y) + (s.z + s.w);
    }
    #pragma unroll
    for (int o = 32; o; o >>= 1) part += __shfl_xor(part, o);
    float inv = 1.0f / part;
    float ej = 0.0f;
    #pragma unroll
    for (int r = 0; r < 4; r++) {
        float4 p;
        p.x = h[r].x * inv; p.y = h[r].y * inv; p.z = h[r].z * inv; p.w = h[r].w * inv;
        ((float4*)(sh + nn * 1024))[lane * 4 + r] = p;
        ej -= p.x * __logf(p.x + EPSR) + p.y * __logf(p.y + EPSR)
            + p.z * __logf(p.z + EPSR) + p.w * __logf(p.w + EPSR);
    }
    #pragma unroll
    for (int o = 32; o; o >>= 1) ej += __shfl_xor(ej, o);
    __syncthreads();
    float m = 0.0f;
    if (lane < 32) {
        int row = lane;
        for (int jj = 0; jj < 32; jj++) m += sh[nn * 1024 + row * 32 + ((jj + row) & 31)];
    } else {
        int col = lane - 32;
        for (int i = 0; i < 32; i++) m += sh[nn * 1024 + i * 32 + col];
    }
    float rc = -m * __logf(m + EPSR);
    #pragma unroll
    for (int o = 16; o; o >>= 1) rc += __shfl_xor(rc, o);   // halves reduce separately
    float es = __shfl(rc, 32);
    if (lane == 0) wres[nn] = (rc + es) / ej;
    __syncthreads();
    if (t == 0)
        out[0] = -(wres[0] + wres[1] + wres[2] + wres[3]) * 0.25f;
}

extern "C" void kernel_launch(void* const* d_in, const int* in_sizes, int n_in,
                              void* d_out, int out_size, void* d_ws, size_t ws_size,
                              hipStream_t stream) {
    const float* tar = (const float*)d_in[0];
    const float* src = (const float*)d_in[1];
    float* out = (float*)d_out;
    float* histall = (float*)d_ws;                         // 32768 floats
    unsigned* counterB = (unsigned*)(histall + 32768);     // zeroed by k_minmax
    float4* pw = (float4*)(histall + 33024);               // 864 float4

    k_minmax<<<dim3(MM_BPS, N_SAMPLES), 256, 0, stream>>>(tar, src, pw, histall);
    k_hist<<<dim3(H_BPS, N_SAMPLES), 256, 0, stream>>>(tar, src, pw, histall,
                                                       counterB, out);
}

// Round 4
// 104.468 us; speedup vs baseline: 2.5156x; 2.2710x over previous
//
#include <hip/hip_runtime.h>
#include <math.h>

#define N_SAMPLES 4
#define P_ELEMS   (96*96*96)          // 884736
// minmax geometry: deep loads, pure BW
#define MM_BPS    216
#define MM_T4     1024                // float4 per array per block (4/thread)
// hist geometry: validated MFMA loop
#define H_BPS     432
#define H_TILE    2048
#define H_T4      (H_TILE/4)          // 512 float4; 2 per thread per array
#define NCOPY     8                   // replicated global hists (contention / XCD spread)
// weight = exp(-(xb-k)^2 * 2048/961) = exp2(-((xb-k)*WS)^2), WS = sqrt(2048/961*log2 e)
#define WS        1.75343855f
// bf16 bits of 2^(-s):  u16 = sat_u32( s*(-128) + MAGIC ),  MAGIC = 127*128 - 3.3
// (zero-mean multiplicative error vs true exp2; |err| <= ~4%, mean ~0)
#define MAGIC_E2  16252.7f
#define EPSR      1e-10f

typedef __attribute__((ext_vector_type(8)))  short short8;
typedef __attribute__((ext_vector_type(16))) float float16;
typedef __attribute__((ext_vector_type(2)))  float float2v;

// ws: pw[1728] float4 ; hist[NCOPY][4][1024] floats
#define PW_COUNT  (N_SAMPLES * H_BPS)

// ---------------- dispatch 1: per-block minmax partials + hist zeroing ----------------

__global__ void __launch_bounds__(256)
k_minmax(const float* __restrict__ tar, const float* __restrict__ src,
         float4* __restrict__ pw, float* __restrict__ histall) {
    __shared__ float4 sred[4];
    int n = blockIdx.y, j = blockIdx.x;
    int t = threadIdx.x;
    const float4* t4 = (const float4*)(tar + (size_t)n * P_ELEMS) + (size_t)j * MM_T4;
    const float4* s4 = (const float4*)(src + (size_t)n * P_ELEMS) + (size_t)j * MM_T4;
    float4 a0 = t4[t], a1 = t4[t + 256], a2 = t4[t + 512], a3 = t4[t + 768];
    float4 b0 = s4[t], b1 = s4[t + 256], b2 = s4[t + 512], b3 = s4[t + 768];
    float mnt = fminf(fminf(fminf(a0.x, a0.y), fminf(a0.z, a0.w)),
                      fminf(fminf(a1.x, a1.y), fminf(a1.z, a1.w)));
    mnt = fminf(mnt, fminf(fminf(fminf(a2.x, a2.y), fminf(a2.z, a2.w)),
                           fminf(fminf(a3.x, a3.y), fminf(a3.z, a3.w))));
    float mxt = fmaxf(fmaxf(fmaxf(a0.x, a0.y), fmaxf(a0.z, a0.w)),
                      fmaxf(fmaxf(a1.x, a1.y), fmaxf(a1.z, a1.w)));
    mxt = fmaxf(mxt, fmaxf(fmaxf(fmaxf(a2.x, a2.y), fmaxf(a2.z, a2.w)),
                           fmaxf(fmaxf(a3.x, a3.y), fmaxf(a3.z, a3.w))));
    float mns = fminf(fminf(fminf(b0.x, b0.y), fminf(b0.z, b0.w)),
                      fminf(fminf(b1.x, b1.y), fminf(b1.z, b1.w)));
    mns = fminf(mns, fminf(fminf(fminf(b2.x, b2.y), fminf(b2.z, b2.w)),
                           fminf(fminf(b3.x, b3.y), fminf(b3.z, b3.w))));
    float mxs = fmaxf(fmaxf(fmaxf(b0.x, b0.y), fmaxf(b0.z, b0.w)),
                      fmaxf(fmaxf(b1.x, b1.y), fmaxf(b1.z, b1.w)));
    mxs = fmaxf(mxs, fmaxf(fmaxf(fmaxf(b2.x, b2.y), fmaxf(b2.z, b2.w)),
                           fmaxf(fmaxf(b3.x, b3.y), fmaxf(b3.z, b3.w))));
    #pragma unroll
    for (int o = 32; o; o >>= 1) {
        mnt = fminf(mnt, __shfl_xor(mnt, o));
        mxt = fmaxf(mxt, __shfl_xor(mxt, o));
        mns = fminf(mns, __shfl_xor(mns, o));
        mxs = fmaxf(mxs, __shfl_xor(mxs, o));
    }
    int lane = t & 63, wave = t >> 6;
    if (lane == 0) sred[wave] = make_float4(mnt, mxt, mns, mxs);
    __syncthreads();
    if (t == 0) {
        float4 v0 = sred[0], v1 = sred[1], v2 = sred[2], v3 = sred[3];
        float4 r;
        r.x = fminf(fminf(v0.x, v1.x), fminf(v2.x, v3.x));
        r.y = fmaxf(fmaxf(v0.y, v1.y), fmaxf(v2.y, v3.y));
        r.z = fminf(fminf(v0.z, v1.z), fminf(v2.z, v3.z));
        r.w = fmaxf(fmaxf(v0.w, v1.w), fmaxf(v2.w, v3.w));
        pw[n * MM_BPS + j] = r;
    }
    int bid = n * MM_BPS + j;
    if (bid < 128) histall[bid * 256 + t] = 0.0f;    // zero 8*4*1024 floats
}

// ---------------- dispatch 2: MFMA joint histogram ----------------
// A-frag: lane (g=lane>>5, c=lane&31) supplies A[c][8g+j], B[8g+j][c], j=0..7.
// C/D: col = lane&31, row = (reg&3) + 8*(reg>>2) + 4*g.  (validated, absmax 0)

__global__ void __launch_bounds__(256, 4)
k_hist(const float* __restrict__ tar, const float* __restrict__ src,
       const float4* __restrict__ pw, float* __restrict__ histall) {
    __shared__ __align__(16) float lds[2 * H_TILE];  // 16 KB
    __shared__ float4 sred[4];
    __shared__ float bc[4];
    int n = blockIdx.y, j = blockIdx.x;
    int t = threadIdx.x;

    // issue the big input loads first; they retire while we reduce partials
    const float4* t4 = (const float4*)(tar + (size_t)n * P_ELEMS) + (size_t)j * H_T4;
    const float4* s4 = (const float4*)(src + (size_t)n * P_ELEMS) + (size_t)j * H_T4;
    float4 a0 = t4[t], a1 = t4[t + 256];
    float4 b0 = s4[t], b1 = s4[t + 256];

    // reduce the sample's 216 minmax partials (L2-hot)
    {
        const float4* pwn = pw + n * MM_BPS;
        float mnt = INFINITY, mxt = -INFINITY, mns = INFINITY, mxs = -INFINITY;
        if (t < MM_BPS) {
            float4 v = pwn[t];
            mnt = v.x; mxt = v.y; mns = v.z; mxs = v.w;
        }
        #pragma unroll
        for (int o = 32; o; o >>= 1) {
            mnt = fminf(mnt, __shfl_xor(mnt, o));
            mxt = fmaxf(mxt, __shfl_xor(mxt, o));
            mns = fminf(mns, __shfl_xor(mns, o));
            mxs = fmaxf(mxs, __shfl_xor(mxs, o));
        }
        int lane = t & 63, wave = t >> 6;
        if (lane == 0) sred[wave] = make_float4(mnt, mxt, mns, mxs);
        __syncthreads();
        if (t == 0) {
            float4 v0 = sred[0], v1 = sred[1], v2 = sred[2], v3 = sred[3];
            bc[0] = fminf(fminf(v0.x, v1.x), fminf(v2.x, v3.x));
            bc[1] = fmaxf(fmaxf(v0.y, v1.y), fmaxf(v2.y, v3.y));
            bc[2] = fminf(fminf(v0.z, v1.z), fminf(v2.z, v3.z));
            bc[3] = fmaxf(fmaxf(v0.w, v1.w), fmaxf(v2.w, v3.w));
        }
        __syncthreads();
    }
    float mnt = bc[0], mns = bc[2];
    float fit = 31.0f * WS / (bc[1] - mnt + 1e-12f);
    float fis = 31.0f * WS / (bc[3] - mns + 1e-12f);

    // stage pre-scaled bin coords
    {
        float4 xo, yo;
        xo.x = (a0.x - mnt) * fit; xo.y = (a0.y - mnt) * fit;
        xo.z = (a0.z - mnt) * fit; xo.w = (a0.w - mnt) * fit;
        ((float4*)lds)[t] = xo;
        xo.x = (a1.x - mnt) * fit; xo.y = (a1.y - mnt) * fit;
        xo.z = (a1.z - mnt) * fit; xo.w = (a1.w - mnt) * fit;
        ((float4*)lds)[t + 256] = xo;
        yo.x = (b0.x - mns) * fis; yo.y = (b0.y - mns) * fis;
        yo.z = (b0.z - mns) * fis; yo.w = (b0.w - mns) * fis;
        ((float4*)(lds + H_TILE))[t] = yo;
        yo.x = (b1.x - mns) * fis; yo.y = (b1.y - mns) * fis;
        yo.z = (b1.z - mns) * fis; yo.w = (b1.w - mns) * fis;
        ((float4*)(lds + H_TILE))[t + 256] = yo;
    }
    __syncthreads();

    int lane = t & 63, wave = t >> 6, g = lane >> 5;
    float q = (float)(lane & 31) * WS;
    const float* xb = lds + wave * (H_TILE / 4);
    const float* yb = lds + H_TILE + wave * (H_TILE / 4);

    const float2v nq2 = {-q, -q};
    const float2v nk2 = {-128.0f, -128.0f};
    const float2v mg2 = {MAGIC_E2, MAGIC_E2};

    float16 acc;
    #pragma unroll
    for (int i = 0; i < 16; i++) acc[i] = 0.0f;

    #pragma unroll 4
    for (int it = 0; it < H_TILE / 4 / 16; it++) {   // 32 iterations, 16 elements each
        int kb = it * 16 + g * 8;
        float4 xa = *(const float4*)(xb + kb);
        float4 xc = *(const float4*)(xb + kb + 4);
        float4 ya = *(const float4*)(yb + kb);
        float4 yc = *(const float4*)(yb + kb + 4);
        float2v xp[4] = {{xa.x, xa.y}, {xa.z, xa.w}, {xc.x, xc.y}, {xc.z, xc.w}};
        float2v yp[4] = {{ya.x, ya.y}, {ya.z, ya.w}, {yc.x, yc.y}, {yc.z, yc.w}};
        union { unsigned u[4]; short8 v; } af, bf;
        #pragma unroll
        for (int jj = 0; jj < 4; jj++) {
            // d = x - q ; s = d*d ; u = s*(-128) + MAGIC ; bf16bits = sat_u32(u)
            float2v d  = xp[jj] + nq2;
            float2v s  = d * d;
            float2v u  = s * nk2 + mg2;      // v_pk_fma_f32
            unsigned w0, w1;
            asm("v_cvt_u32_f32 %0, %1" : "=v"(w0) : "v"(u.x));   // saturates neg -> 0
            asm("v_cvt_u32_f32 %0, %1" : "=v"(w1) : "v"(u.y));
            af.u[jj] = (w1 << 16) | w0;
            d  = yp[jj] + nq2;
            s  = d * d;
            u  = s * nk2 + mg2;
            asm("v_cvt_u32_f32 %0, %1" : "=v"(w0) : "v"(u.x));
            asm("v_cvt_u32_f32 %0, %1" : "=v"(w1) : "v"(u.y));
            bf.u[jj] = (w1 << 16) | w0;
        }
        acc = __builtin_amdgcn_mfma_f32_32x32x16_bf16(af.v, bf.v, acc, 0, 0, 0);
    }

    __syncthreads();
    {
        float* hw = lds + wave * 1024;
        int col = lane & 31;
        #pragma unroll
        for (int reg = 0; reg < 16; reg++) {
            int row = (reg & 3) + 8 * (reg >> 2) + 4 * g;
            hw[row * 32 + col] = acc[reg];
        }
    }
    __syncthreads();
    // merge into one of NCOPY replicated hists (spread over XCD round-robin)
    float* histn = histall + ((j & (NCOPY - 1)) * N_SAMPLES + n) * 1024;
    for (int bb = t; bb < 1024; bb += 256) {
        float v = lds[bb] + lds[1024 + bb] + lds[2048 + bb] + lds[3072 + bb];
        unsafeAtomicAdd(&histn[bb], v);
    }
}

// ---------------- dispatch 3: entropies + loss ----------------

__global__ void __launch_bounds__(256)
k_final(const float* __restrict__ histall, float* __restrict__ out) {
    __shared__ float sh[4096];
    __shared__ float wres[4];
    int t = threadIdx.x;
    int lane = t & 63, nn = t >> 6;
    float4 h[4];
    float part = 0.0f;
    #pragma unroll
    for (int r = 0; r < 4; r++) {
        float4 s = make_float4(0.f, 0.f, 0.f, 0.f);
        #pragma unroll
        for (int c = 0; c < NCOPY; c++) {
            const float4* h4 = (const float4*)(histall + (c * N_SAMPLES + nn) * 1024);
            float4 v = h4[lane * 4 + r];
            s.x += v.x; s.y += v.y; s.z += v.z; s.w += v.w;
        }
        h[r] = s;
        part += (s.x + s.y) + (s.z + s.w);
    }
    #pragma unroll
    for (int o = 32; o; o >>= 1) part += __shfl_xor(part, o);
    float inv = 1.0f / part;
    float ej = 0.0f;
    #pragma unroll
    for (int r = 0; r < 4; r++) {
        float4 p;
        p.x = h[r].x * inv; p.y = h[r].y * inv; p.z = h[r].z * inv; p.w = h[r].w * inv;
        ((float4*)(sh + nn * 1024))[lane * 4 + r] = p;
        ej -= p.x * __logf(p.x + EPSR) + p.y * __logf(p.y + EPSR)
            + p.z * __logf(p.z + EPSR) + p.w * __logf(p.w + EPSR);
    }
    #pragma unroll
    for (int o = 32; o; o >>= 1) ej += __shfl_xor(ej, o);
    __syncthreads();
    float m = 0.0f;
    if (lane < 32) {
        int row = lane;
        for (int jj = 0; jj < 32; jj++) m += sh[nn * 1024 + row * 32 + ((jj + row) & 31)];
    } else {
        int col = lane - 32;
        for (int i = 0; i < 32; i++) m += sh[nn * 1024 + i * 32 + col];
    }
    float rc = -m * __logf(m + EPSR);
    #pragma unroll
    for (int o = 16; o; o >>= 1) rc += __shfl_xor(rc, o);   // halves reduce separately
    float es = __shfl(rc, 32);
    if (lane == 0) wres[nn] = (rc + es) / ej;
    __syncthreads();
    if (t == 0)
        out[0] = -(wres[0] + wres[1] + wres[2] + wres[3]) * 0.25f;
}

extern "C" void kernel_launch(void* const* d_in, const int* in_sizes, int n_in,
                              void* d_out, int out_size, void* d_ws, size_t ws_size,
                              hipStream_t stream) {
    const float* tar = (const float*)d_in[0];
    const float* src = (const float*)d_in[1];
    float* out = (float*)d_out;
    float4* pw = (float4*)d_ws;                                  // 864 used (alloc 1728 slots)
    float* histall = (float*)((char*)d_ws + PW_COUNT * 16);      // NCOPY*4*1024 floats

    k_minmax<<<dim3(MM_BPS, N_SAMPLES), 256, 0, stream>>>(tar, src, pw, histall);
    k_hist<<<dim3(H_BPS, N_SAMPLES), 256, 0, stream>>>(tar, src, pw, histall);
    k_final<<<1, 256, 0, stream>>>(histall, out);
}

// Round 5
// 96.229 us; speedup vs baseline: 2.7309x; 1.0856x over previous
//
#include <hip/hip_runtime.h>
#include <math.h>

#define N_SAMPLES 4
#define P_ELEMS   (96*96*96)          // 884736
// minmax geometry: deep loads, pure BW
#define MM_BPS    216
#define MM_T4     1024                // float4 per array per block (4/thread)
// hist geometry: validated MFMA loop
#define H_BPS     432
#define H_TILE    2048
#define H_T4      (H_TILE/4)          // 512 float4; 2 per thread per array
#define NCOPY     8                   // replicated global hists (contention / XCD spread)
// weight = exp(-(xb-k)^2 * 2048/961) = exp2(-((xb-k)*WS)^2), WS = sqrt(2048/961*log2 e)
#define WS        1.75343855f
// bf16 bits of 2^(-s):  u16 = round( s*(-128) + MAGIC ),  MAGIC tuned for round-to-nearest
// (zero-mean multiplicative error vs true exp2; |err| <= ~4%, mean ~0)
#define MAGIC_E2  16252.2f
#define EPSR      1e-10f

typedef __attribute__((ext_vector_type(8)))  short short8;
typedef __attribute__((ext_vector_type(16))) float float16;
typedef __attribute__((ext_vector_type(2)))  float float2v;

// ws: pw[1728] float4 ; hist[NCOPY][4][1024] floats
#define PW_COUNT  (N_SAMPLES * H_BPS)

// ---------------- dispatch 1: per-block minmax partials + hist zeroing ----------------

__global__ void __launch_bounds__(256)
k_minmax(const float* __restrict__ tar, const float* __restrict__ src,
         float4* __restrict__ pw, float* __restrict__ histall) {
    __shared__ float4 sred[4];
    int n = blockIdx.y, j = blockIdx.x;
    int t = threadIdx.x;
    const float4* t4 = (const float4*)(tar + (size_t)n * P_ELEMS) + (size_t)j * MM_T4;
    const float4* s4 = (const float4*)(src + (size_t)n * P_ELEMS) + (size_t)j * MM_T4;
    float4 a0 = t4[t], a1 = t4[t + 256], a2 = t4[t + 512], a3 = t4[t + 768];
    float4 b0 = s4[t], b1 = s4[t + 256], b2 = s4[t + 512], b3 = s4[t + 768];
    float mnt = fminf(fminf(fminf(a0.x, a0.y), fminf(a0.z, a0.w)),
                      fminf(fminf(a1.x, a1.y), fminf(a1.z, a1.w)));
    mnt = fminf(mnt, fminf(fminf(fminf(a2.x, a2.y), fminf(a2.z, a2.w)),
                           fminf(fminf(a3.x, a3.y), fminf(a3.z, a3.w))));
    float mxt = fmaxf(fmaxf(fmaxf(a0.x, a0.y), fmaxf(a0.z, a0.w)),
                      fmaxf(fmaxf(a1.x, a1.y), fmaxf(a1.z, a1.w)));
    mxt = fmaxf(mxt, fmaxf(fmaxf(fmaxf(a2.x, a2.y), fmaxf(a2.z, a2.w)),
                           fmaxf(fmaxf(a3.x, a3.y), fmaxf(a3.z, a3.w))));
    float mns = fminf(fminf(fminf(b0.x, b0.y), fminf(b0.z, b0.w)),
                      fminf(fminf(b1.x, b1.y), fminf(b1.z, b1.w)));
    mns = fminf(mns, fminf(fminf(fminf(b2.x, b2.y), fminf(b2.z, b2.w)),
                           fminf(fminf(b3.x, b3.y), fminf(b3.z, b3.w))));
    float mxs = fmaxf(fmaxf(fmaxf(b0.x, b0.y), fmaxf(b0.z, b0.w)),
                      fmaxf(fmaxf(b1.x, b1.y), fmaxf(b1.z, b1.w)));
    mxs = fmaxf(mxs, fmaxf(fmaxf(fmaxf(b2.x, b2.y), fmaxf(b2.z, b2.w)),
                           fmaxf(fmaxf(b3.x, b3.y), fmaxf(b3.z, b3.w))));
    #pragma unroll
    for (int o = 32; o; o >>= 1) {
        mnt = fminf(mnt, __shfl_xor(mnt, o));
        mxt = fmaxf(mxt, __shfl_xor(mxt, o));
        mns = fminf(mns, __shfl_xor(mns, o));
        mxs = fmaxf(mxs, __shfl_xor(mxs, o));
    }
    int lane = t & 63, wave = t >> 6;
    if (lane == 0) sred[wave] = make_float4(mnt, mxt, mns, mxs);
    __syncthreads();
    if (t == 0) {
        float4 v0 = sred[0], v1 = sred[1], v2 = sred[2], v3 = sred[3];
        float4 r;
        r.x = fminf(fminf(v0.x, v1.x), fminf(v2.x, v3.x));
        r.y = fmaxf(fmaxf(v0.y, v1.y), fmaxf(v2.y, v3.y));
        r.z = fminf(fminf(v0.z, v1.z), fminf(v2.z, v3.z));
        r.w = fmaxf(fmaxf(v0.w, v1.w), fmaxf(v2.w, v3.w));
        pw[n * MM_BPS + j] = r;
    }
    int bid = n * MM_BPS + j;
    if (bid < 128) histall[bid * 256 + t] = 0.0f;    // zero 8*4*1024 floats
}

// ---------------- dispatch 2: MFMA joint histogram ----------------
// A-frag: lane (g=lane>>5, c=lane&31) supplies A[c][8g+j], B[8g+j][c], j=0..7.
// C/D: col = lane&31, row = (reg&3) + 8*(reg>>2) + 4*g.  (validated, absmax 0)
// Weight bits via per-lane quadratic in RAW x:
//   u''(x) = (A + B x + C x^2),  u16 = pknorm_u16(u'') = round(clamp(u'',0,1)*65535)
//   with A,B,C pre-scaled by 1/65535 so that 65535*u'' = MAGIC - 128*(fit*x + e - q)^2.
// Negative exponent-field (true underflow) saturates to 0 via pknorm clamp.

__global__ void __launch_bounds__(256, 4)
k_hist(const float* __restrict__ tar, const float* __restrict__ src,
       const float4* __restrict__ pw, float* __restrict__ histall) {
    __shared__ __align__(16) float lds[2 * H_TILE];  // 16 KB
    __shared__ float4 sred[4];
    __shared__ float bc[4];
    int n = blockIdx.y, j = blockIdx.x;
    int t = threadIdx.x;

    // issue the big input loads first; they retire while we reduce partials
    const float4* t4 = (const float4*)(tar + (size_t)n * P_ELEMS) + (size_t)j * H_T4;
    const float4* s4 = (const float4*)(src + (size_t)n * P_ELEMS) + (size_t)j * H_T4;
    float4 a0 = t4[t], a1 = t4[t + 256];
    float4 b0 = s4[t], b1 = s4[t + 256];

    // reduce the sample's 216 minmax partials (L2-hot)
    {
        const float4* pwn = pw + n * MM_BPS;
        float mnt = INFINITY, mxt = -INFINITY, mns = INFINITY, mxs = -INFINITY;
        if (t < MM_BPS) {
            float4 v = pwn[t];
            mnt = v.x; mxt = v.y; mns = v.z; mxs = v.w;
        }
        #pragma unroll
        for (int o = 32; o; o >>= 1) {
            mnt = fminf(mnt, __shfl_xor(mnt, o));
            mxt = fmaxf(mxt, __shfl_xor(mxt, o));
            mns = fminf(mns, __shfl_xor(mns, o));
            mxs = fmaxf(mxs, __shfl_xor(mxs, o));
        }
        int lane = t & 63, wave = t >> 6;
        if (lane == 0) sred[wave] = make_float4(mnt, mxt, mns, mxs);
    }

    // stage RAW inputs (no arithmetic needed — normalize folded into weight poly)
    ((float4*)lds)[t]                  = a0;
    ((float4*)lds)[t + 256]            = a1;
    ((float4*)(lds + H_TILE))[t]       = b0;
    ((float4*)(lds + H_TILE))[t + 256] = b1;

    __syncthreads();
    if (t == 0) {
        float4 v0 = sred[0], v1 = sred[1], v2 = sred[2], v3 = sred[3];
        bc[0] = fminf(fminf(v0.x, v1.x), fminf(v2.x, v3.x));
        bc[1] = fmaxf(fmaxf(v0.y, v1.y), fmaxf(v2.y, v3.y));
        bc[2] = fminf(fminf(v0.z, v1.z), fminf(v2.z, v3.z));
        bc[3] = fmaxf(fmaxf(v0.w, v1.w), fmaxf(v2.w, v3.w));
    }
    __syncthreads();

    int lane = t & 63, wave = t >> 6, g = lane >> 5;
    float q = (float)(lane & 31) * WS;

    // per-lane quadratic coefficients (scaled by 1/65535 for pknorm)
    const float INV = 1.0f / 65535.0f;
    float ht = 31.0f * WS / (bc[1] - bc[0] + 1e-12f);
    float rt = -ht * bc[0] - q;
    float hs = 31.0f * WS / (bc[3] - bc[2] + 1e-12f);
    float rs = -hs * bc[2] - q;
    float At = (MAGIC_E2 - 128.0f * rt * rt) * INV;
    float Bt = (-256.0f * ht * rt) * INV;
    float Ct = (-128.0f * ht * ht) * INV;
    float As = (MAGIC_E2 - 128.0f * rs * rs) * INV;
    float Bs = (-256.0f * hs * rs) * INV;
    float Cs = (-128.0f * hs * hs) * INV;
    const float2v At2 = {At, At}, Bt2 = {Bt, Bt}, Ct2 = {Ct, Ct};
    const float2v As2 = {As, As}, Bs2 = {Bs, Bs}, Cs2 = {Cs, Cs};

    const float* xb = lds + wave * (H_TILE / 4);
    const float* yb = lds + H_TILE + wave * (H_TILE / 4);

    float16 acc;
    #pragma unroll
    for (int i = 0; i < 16; i++) acc[i] = 0.0f;

    #pragma unroll 4
    for (int it = 0; it < H_TILE / 4 / 16; it++) {   // 32 iterations, 16 elements each
        int kb = it * 16 + g * 8;
        float4 xa = *(const float4*)(xb + kb);
        float4 xc = *(const float4*)(xb + kb + 4);
        float4 ya = *(const float4*)(yb + kb);
        float4 yc = *(const float4*)(yb + kb + 4);
        float2v xp[4] = {{xa.x, xa.y}, {xa.z, xa.w}, {xc.x, xc.y}, {xc.z, xc.w}};
        float2v yp[4] = {{ya.x, ya.y}, {ya.z, ya.w}, {yc.x, yc.y}, {yc.z, yc.w}};
        union { unsigned u[4]; short8 v; } af, bf;
        #pragma unroll
        for (int jj = 0; jj < 4; jj++) {
            // u'' = (C*x + B)*x + A  — two v_pk_fma_f32, then one packed cvt
            float2v tt = xp[jj] * Ct2 + Bt2;
            float2v uu = tt * xp[jj] + At2;
            asm("v_cvt_pknorm_u16_f32 %0, %1, %2"
                : "=v"(af.u[jj]) : "v"(uu.x), "v"(uu.y));
            tt = yp[jj] * Cs2 + Bs2;
            uu = tt * yp[jj] + As2;
            asm("v_cvt_pknorm_u16_f32 %0, %1, %2"
                : "=v"(bf.u[jj]) : "v"(uu.x), "v"(uu.y));
        }
        acc = __builtin_amdgcn_mfma_f32_32x32x16_bf16(af.v, bf.v, acc, 0, 0, 0);
    }

    __syncthreads();
    {
        float* hw = lds + wave * 1024;
        int col = lane & 31;
        #pragma unroll
        for (int reg = 0; reg < 16; reg++) {
            int row = (reg & 3) + 8 * (reg >> 2) + 4 * g;
            hw[row * 32 + col] = acc[reg];
        }
    }
    __syncthreads();
    // merge into one of NCOPY replicated hists (spread over XCD round-robin)
    float* histn = histall + ((j & (NCOPY - 1)) * N_SAMPLES + n) * 1024;
    for (int bb = t; bb < 1024; bb += 256) {
        float v = lds[bb] + lds[1024 + bb] + lds[2048 + bb] + lds[3072 + bb];
        unsafeAtomicAdd(&histn[bb], v);
    }
}

// ---------------- dispatch 3: entropies + loss ----------------

__global__ void __launch_bounds__(256)
k_final(const float* __restrict__ histall, float* __restrict__ out) {
    __shared__ float sh[4096];
    __shared__ float wres[4];
    int t = threadIdx.x;
    int lane = t & 63, nn = t >> 6;
    float4 h[4];
    float part = 0.0f;
    #pragma unroll
    for (int r = 0; r < 4; r++) {
        float4 s = make_float4(0.f, 0.f, 0.f, 0.f);
        #pragma unroll
        for (int c = 0; c < NCOPY; c++) {
            const float4* h4 = (const float4*)(histall + (c * N_SAMPLES + nn) * 1024);
            float4 v = h4[lane * 4 + r];
            s.x += v.x; s.y += v.y; s.z += v.z; s.w += v.w;
        }
        h[r] = s;
        part += (s.x + s.y) + (s.z + s.w);
    }
    #pragma unroll
    for (int o = 32; o; o >>= 1) part += __shfl_xor(part, o);
    float inv = 1.0f / part;
    float ej = 0.0f;
    #pragma unroll
    for (int r = 0; r < 4; r++) {
        float4 p;
        p.x = h[r].x * inv; p.y = h[r].y * inv; p.z = h[r].z * inv; p.w = h[r].w * inv;
        ((float4*)(sh + nn * 1024))[lane * 4 + r] = p;
        ej -= p.x * __logf(p.x + EPSR) + p.y * __logf(p.y + EPSR)
            + p.z * __logf(p.z + EPSR) + p.w * __logf(p.w + EPSR);
    }
    #pragma unroll
    for (int o = 32; o; o >>= 1) ej += __shfl_xor(ej, o);
    __syncthreads();
    float m = 0.0f;
    if (lane < 32) {
        int row = lane;
        for (int jj = 0; jj < 32; jj++) m += sh[nn * 1024 + row * 32 + ((jj + row) & 31)];
    } else {
        int col = lane - 32;
        for (int i = 0; i < 32; i++) m += sh[nn * 1024 + i * 32 + col];
    }
    float rc = -m * __logf(m + EPSR);
    #pragma unroll
    for (int o = 16; o; o >>= 1) rc += __shfl_xor(rc, o);   // halves reduce separately
    float es = __shfl(rc, 32);
    if (lane == 0) wres[nn] = (rc + es) / ej;
    __syncthreads();
    if (t == 0)
        out[0] = -(wres[0] + wres[1] + wres[2] + wres[3]) * 0.25f;
}

extern "C" void kernel_launch(void* const* d_in, const int* in_sizes, int n_in,
                              void* d_out, int out_size, void* d_ws, size_t ws_size,
                              hipStream_t stream) {
    const float* tar = (const float*)d_in[0];
    const float* src = (const float*)d_in[1];
    float* out = (float*)d_out;
    float4* pw = (float4*)d_ws;                                  // 864 used (alloc 1728 slots)
    float* histall = (float*)((char*)d_ws + PW_COUNT * 16);      // NCOPY*4*1024 floats

    k_minmax<<<dim3(MM_BPS, N_SAMPLES), 256, 0, stream>>>(tar, src, pw, histall);
    k_hist<<<dim3(H_BPS, N_SAMPLES), 256, 0, stream>>>(tar, src, pw, histall);
    k_final<<<1, 256, 0, stream>>>(histall, out);
}